// Round 3
// baseline (1248.706 us; speedup 1.0000x reference)
//
#include <hip/hip_runtime.h>
#include <math.h>

#define NN 100000
#define NE 3200000
#define NB 391            // buckets of 256 nodes: ceil(100000/256)
#define CH 4096           // edges per partition chunk
#define NPART ((NE + CH - 1) / CH)   // 782 partition blocks
#define NB1 ((NN + 255) / 256)

// ---------------- bucket histogram: bhist[dst>>8]++ ----------------
__global__ void bhist_kernel(const int* __restrict__ dst, int* __restrict__ bhist, int e) {
    __shared__ int h[NB];
    int tid = threadIdx.x;
    for (int i = tid; i < NB; i += 256) h[i] = 0;
    __syncthreads();
    for (int i = blockIdx.x * blockDim.x + tid; i < e; i += gridDim.x * blockDim.x)
        atomicAdd(&h[dst[i] >> 8], 1);
    __syncthreads();
    for (int i = tid; i < NB; i += 256) if (h[i]) atomicAdd(&bhist[i], h[i]);
}

// ---------------- bucket scan: boffs = exclusive(bhist); cursor = boffs ----------------
__global__ void bscan_kernel(const int* __restrict__ bhist, int* __restrict__ boffs,
                             int* __restrict__ cursor) {
    __shared__ int s[512];
    int tid = threadIdx.x;
    int v = (tid < NB) ? bhist[tid] : 0;
    s[tid] = v;
    __syncthreads();
    for (int off = 1; off < 512; off <<= 1) {
        int t = (tid >= off) ? s[tid - off] : 0;
        __syncthreads();
        s[tid] += t;
        __syncthreads();
    }
    if (tid < NB) {
        int ex = s[tid] - v;
        boffs[tid] = ex;
        cursor[tid] = ex;
    }
}

// ---------------- partition: bucketed counting-sort with LDS-staged coalesced writes ----------------
__global__ __launch_bounds__(256) void partition_kernel(
        const int* __restrict__ src, const int* __restrict__ dst,
        int* __restrict__ cursor, int* __restrict__ adj, int e) {
    __shared__ int scnt[NB];
    __shared__ int sbase[NB];
    __shared__ int lexcl[NB];
    __shared__ int sA[512], sB[512];
    __shared__ int sdata[CH];
    __shared__ unsigned short srank[CH];
    __shared__ unsigned short pbuk[CH];

    int tid = threadIdx.x;
    int chunk0 = blockIdx.x * CH;
    int cnt = e - chunk0; if (cnt > CH) cnt = CH;

    for (int i = tid; i < NB; i += 256) scnt[i] = 0;
    __syncthreads();

    // phase 1: local ranks via LDS atomic histogram
    for (int k = 0; k < CH / 256; ++k) {
        int li = k * 256 + tid;
        int i = chunk0 + li;
        if (i < e) {
            int b = dst[i] >> 8;
            int r = atomicAdd(&scnt[b], 1);
            srank[li] = (unsigned short)r;
        }
    }
    __syncthreads();

    // phase 2: reserve global space per bucket
    for (int b = tid; b < NB; b += 256)
        if (scnt[b]) sbase[b] = atomicAdd(&cursor[b], scnt[b]);

    // phase 3: exclusive scan of scnt -> lexcl (double-buffered Hillis-Steele over 512)
    {
        int* pa = sA; int* pb = sB;
        pa[tid]       = (tid < NB) ? scnt[tid] : 0;
        pa[tid + 256] = (tid + 256 < NB) ? scnt[tid + 256] : 0;
        __syncthreads();
        for (int off = 1; off < 512; off <<= 1) {
            for (int q = tid; q < 512; q += 256)
                pb[q] = pa[q] + ((q >= off) ? pa[q - off] : 0);
            __syncthreads();
            int* t = pa; pa = pb; pb = t;
        }
        if (tid < NB)       lexcl[tid]       = pa[tid]       - scnt[tid];
        if (tid + 256 < NB) lexcl[tid + 256] = pa[tid + 256] - scnt[tid + 256];
    }
    __syncthreads();

    // phase 4: scatter into LDS in bucket-sorted order
    for (int k = 0; k < CH / 256; ++k) {
        int li = k * 256 + tid;
        int i = chunk0 + li;
        if (i < e) {
            int s = src[i], d = dst[i];
            int b = d >> 8;
            int p = lexcl[b] + (int)srank[li];
            sdata[p] = (s << 8) | (d & 255);
            pbuk[p] = (unsigned short)b;
        }
    }
    __syncthreads();

    // phase 5: coalesced-order emission to global
    for (int p = tid; p < cnt; p += 256) {
        int b = pbuk[p];
        adj[sbase[b] + (p - lexcl[b])] = sdata[p];
    }
}

// ---------------- dinv from bucket-local histogram ----------------
__global__ void dinvb_kernel(const int* __restrict__ bhist, const int* __restrict__ boffs,
                             const int* __restrict__ adj, float* __restrict__ dinv, int n) {
    __shared__ int ncnt[256];
    int tid = threadIdx.x;
    int b = blockIdx.x;
    ncnt[tid] = 0;
    __syncthreads();
    int ebeg = boffs[b], ecnt = bhist[b];
    for (int j = tid; j < ecnt; j += 256)
        atomicAdd(&ncnt[adj[ebeg + j] & 255], 1);
    __syncthreads();
    int node = b * 256 + tid;
    if (node < n) dinv[node] = rsqrtf((float)ncnt[tid] + 1.0f);
}

// ---------------- layer 1 GEMM: g1 = (x @ W1^T) * dinv[row] ----------------
__global__ void gemm1_kernel(const float* __restrict__ x, const float* __restrict__ W1,
                             const float* __restrict__ dinv, float* __restrict__ g1, int n) {
    __shared__ float sWt[64 * 32];
    __shared__ float sX[8 * 64];
    int tid = threadIdx.x;
    for (int idx = tid; idx < 64 * 32; idx += 256) {
        int k = idx >> 5, c = idx & 31;
        sWt[idx] = W1[c * 64 + k];
    }
    int row0 = blockIdx.x * 8;
    for (int idx = tid; idx < 8 * 64; idx += 256) {
        int r = row0 + (idx >> 6);
        sX[idx] = (r < n) ? x[r * 64 + (idx & 63)] : 0.0f;
    }
    __syncthreads();
    int lr = tid >> 5, c = tid & 31;
    int r = row0 + lr;
    if (r < n) {
        float acc = 0.0f;
#pragma unroll
        for (int k = 0; k < 64; ++k) acc += sX[lr * 64 + k] * sWt[k * 32 + c];
        g1[r * 32 + c] = acc * dinv[r];
    }
}

// ---------------- layer 1 aggregation: LDS accumulate per bucket ----------------
__global__ __launch_bounds__(512) void agg1_kernel(
        const int* __restrict__ bhist, const int* __restrict__ boffs,
        const int* __restrict__ adj, const float* __restrict__ dinv,
        const float* __restrict__ g1, const float* __restrict__ b1,
        float* __restrict__ agg1, int n) {
    __shared__ float acc[256 * 32];
    int tid = threadIdx.x;
    int b = blockIdx.x;
    for (int i = tid; i < 256 * 32; i += 512) acc[i] = 0.0f;
    __syncthreads();
    int ebeg = boffs[b], ecnt = bhist[b];
    int c = tid & 31, slot = tid >> 5;       // 16 edge slots
#pragma unroll 4
    for (int j = slot; j < ecnt; j += 16) {
        int w = adj[ebeg + j];
        int s = w >> 8;
        int l = w & 255;
        atomicAdd(&acc[l * 32 + c], g1[s * 32 + c]);
    }
    __syncthreads();
    for (int idx = tid; idx < 256 * 32; idx += 512) {
        int l = idx >> 5, cc = idx & 31;
        int node = b * 256 + l;
        if (node < n)
            agg1[node * 32 + cc] = b1[cc] + dinv[node] * (acc[idx] + g1[node * 32 + cc]);
    }
}

// ---------------- layer 2 GEMM: g2 = (relu(agg1) @ W2^T) * dinv[row] ----------------
__global__ void gemm2_kernel(const float* __restrict__ agg1, const float* __restrict__ W2,
                             const float* __restrict__ dinv, float* __restrict__ g2, int n) {
    __shared__ float sWt[32 * 16];
    __shared__ float sH[16 * 32];
    int tid = threadIdx.x;
    for (int idx = tid; idx < 32 * 16; idx += 256) {
        int k = idx >> 4, c = idx & 15;
        sWt[idx] = W2[c * 32 + k];
    }
    int row0 = blockIdx.x * 16;
    for (int idx = tid; idx < 16 * 32; idx += 256) {
        int r = row0 + (idx >> 5);
        float v = (r < n) ? agg1[r * 32 + (idx & 31)] : 0.0f;
        sH[idx] = fmaxf(v, 0.0f);
    }
    __syncthreads();
    int lr = tid >> 4, c = tid & 15;
    int r = row0 + lr;
    if (r < n) {
        float acc = 0.0f;
#pragma unroll
        for (int k = 0; k < 32; ++k) acc += sH[lr * 32 + k] * sWt[k * 16 + c];
        g2[r * 16 + c] = acc * dinv[r];
    }
}

// ---------------- layer 2 aggregation ----------------
__global__ __launch_bounds__(512) void agg2_kernel(
        const int* __restrict__ bhist, const int* __restrict__ boffs,
        const int* __restrict__ adj, const float* __restrict__ dinv,
        const float* __restrict__ g2, const float* __restrict__ b2,
        float* __restrict__ z, int n) {
    __shared__ float acc[256 * 16];
    int tid = threadIdx.x;
    int b = blockIdx.x;
    for (int i = tid; i < 256 * 16; i += 512) acc[i] = 0.0f;
    __syncthreads();
    int ebeg = boffs[b], ecnt = bhist[b];
    int c = tid & 15, slot = tid >> 4;       // 32 edge slots
#pragma unroll 4
    for (int j = slot; j < ecnt; j += 32) {
        int w = adj[ebeg + j];
        int s = w >> 8;
        int l = w & 255;
        atomicAdd(&acc[l * 16 + c], g2[s * 16 + c]);
    }
    __syncthreads();
    for (int idx = tid; idx < 256 * 16; idx += 512) {
        int l = idx >> 4, cc = idx & 15;
        int node = b * 256 + l;
        if (node < n)
            z[node * 16 + cc] = b2[cc] + dinv[node] * (acc[idx] + g2[node * 16 + cc]);
    }
}

// ---------------- decode ----------------
__global__ void decode_kernel(const int* __restrict__ src, const int* __restrict__ dst,
                              const float* __restrict__ z, float* __restrict__ out, int e) {
    int i = blockIdx.x * blockDim.x + threadIdx.x;
    if (i < e) {
        int s = src[i], d = dst[i];
        const float4* zs = (const float4*)(z + (size_t)s * 16);
        const float4* zd = (const float4*)(z + (size_t)d * 16);
        float acc = 0.0f;
#pragma unroll
        for (int q = 0; q < 4; ++q) {
            float4 a = zs[q], b = zd[q];
            acc += a.x * b.x + a.y * b.y + a.z * b.z + a.w * b.w;
        }
        out[i] = 1.0f / (1.0f + expf(-acc));
    }
}

extern "C" void kernel_launch(void* const* d_in, const int* in_sizes, int n_in,
                              void* d_out, int out_size, void* d_ws, size_t ws_size,
                              hipStream_t stream) {
    const float* x   = (const float*)d_in[0];
    const int* eidx  = (const int*)d_in[1];
    const float* W1  = (const float*)d_in[2];
    const float* b1  = (const float*)d_in[3];
    const float* W2  = (const float*)d_in[4];
    const float* b2  = (const float*)d_in[5];
    float* out = (float*)d_out;

    const int n = NN;
    const int e = NE;
    const int* src = eidx;
    const int* dst = eidx + e;

    // workspace layout
    int* bhist   = (int*)d_ws;                 // NB (pad 512)
    int* boffs   = bhist + 512;                // NB (pad 512)
    int* cursor  = boffs + 512;                // NB (pad 512)
    int* adj     = cursor + 512;               // E
    float* dinv  = (float*)(adj + e);          // N
    float* g1    = dinv + n;                   // N*32
    float* agg1  = g1 + (size_t)n * 32;        // N*32
    float* g2    = agg1 + (size_t)n * 32;      // N*16
    float* z     = g2 + (size_t)n * 16;        // N*16

    dim3 blk(256);

    // CSR-by-bucket build
    hipMemsetAsync(bhist, 0, 512 * sizeof(int), stream);
    bhist_kernel<<<1024, blk, 0, stream>>>(dst, bhist, e);
    bscan_kernel<<<1, 512, 0, stream>>>(bhist, boffs, cursor);
    partition_kernel<<<NPART, blk, 0, stream>>>(src, dst, cursor, adj, e);
    dinvb_kernel<<<NB, blk, 0, stream>>>(bhist, boffs, adj, dinv, n);

    // layer 1
    gemm1_kernel<<<(n + 7) / 8, blk, 0, stream>>>(x, W1, dinv, g1, n);
    agg1_kernel<<<NB, 512, 0, stream>>>(bhist, boffs, adj, dinv, g1, b1, agg1, n);

    // layer 2
    gemm2_kernel<<<(n + 15) / 16, blk, 0, stream>>>(agg1, W2, dinv, g2, n);
    agg2_kernel<<<NB, 512, 0, stream>>>(bhist, boffs, adj, dinv, g2, b2, z, n);

    // decode
    decode_kernel<<<(e + 255) / 256, blk, 0, stream>>>(src, dst, z, out, e);
}

// Round 4
// 392.532 us; speedup vs baseline: 3.1812x; 3.1812x over previous
//
#include <hip/hip_runtime.h>
#include <math.h>

#define NN 100000
#define NE 3200000
#define NB 391            // buckets of 256 nodes
#define CH 4096           // edges per partition chunk
#define NPART ((NE + CH - 1) / CH)   // 782

// ---------------- bucket histogram: bhist[dst>>8]++ ----------------
__global__ void bhist_kernel(const int* __restrict__ dst, int* __restrict__ bhist, int e) {
    __shared__ int h[NB];
    int tid = threadIdx.x;
    for (int i = tid; i < NB; i += 256) h[i] = 0;
    __syncthreads();
    for (int i = blockIdx.x * blockDim.x + tid; i < e; i += gridDim.x * blockDim.x)
        atomicAdd(&h[dst[i] >> 8], 1);
    __syncthreads();
    for (int i = tid; i < NB; i += 256) if (h[i]) atomicAdd(&bhist[i], h[i]);
}

// ---------------- bucket scan ----------------
__global__ void bscan_kernel(const int* __restrict__ bhist, int* __restrict__ boffs,
                             int* __restrict__ cursor) {
    __shared__ int s[512];
    int tid = threadIdx.x;
    int v = (tid < NB) ? bhist[tid] : 0;
    s[tid] = v;
    __syncthreads();
    for (int off = 1; off < 512; off <<= 1) {
        int t = (tid >= off) ? s[tid - off] : 0;
        __syncthreads();
        s[tid] += t;
        __syncthreads();
    }
    if (tid < NB) {
        int ex = s[tid] - v;
        boffs[tid] = ex;
        cursor[tid] = ex;
    }
}

// ---------------- partition: bucketed counting-sort, LDS-staged coalesced writes ----------------
__global__ __launch_bounds__(256) void partition_kernel(
        const int* __restrict__ src, const int* __restrict__ dst,
        int* __restrict__ cursor, int* __restrict__ adj, int e) {
    __shared__ int scnt[NB];
    __shared__ int sbase[NB];
    __shared__ int lexcl[NB];
    __shared__ int sA[512], sB[512];
    __shared__ int sdata[CH];
    __shared__ unsigned short srank[CH];
    __shared__ unsigned short pbuk[CH];

    int tid = threadIdx.x;
    int chunk0 = blockIdx.x * CH;
    int cnt = e - chunk0; if (cnt > CH) cnt = CH;

    for (int i = tid; i < NB; i += 256) scnt[i] = 0;
    __syncthreads();

    for (int k = 0; k < CH / 256; ++k) {
        int li = k * 256 + tid;
        int i = chunk0 + li;
        if (i < e) {
            int b = dst[i] >> 8;
            int r = atomicAdd(&scnt[b], 1);
            srank[li] = (unsigned short)r;
        }
    }
    __syncthreads();

    for (int b = tid; b < NB; b += 256)
        if (scnt[b]) sbase[b] = atomicAdd(&cursor[b], scnt[b]);

    {
        int* pa = sA; int* pb = sB;
        pa[tid]       = (tid < NB) ? scnt[tid] : 0;
        pa[tid + 256] = (tid + 256 < NB) ? scnt[tid + 256] : 0;
        __syncthreads();
        for (int off = 1; off < 512; off <<= 1) {
            for (int q = tid; q < 512; q += 256)
                pb[q] = pa[q] + ((q >= off) ? pa[q - off] : 0);
            __syncthreads();
            int* t = pa; pa = pb; pb = t;
        }
        if (tid < NB)       lexcl[tid]       = pa[tid]       - scnt[tid];
        if (tid + 256 < NB) lexcl[tid + 256] = pa[tid + 256] - scnt[tid + 256];
    }
    __syncthreads();

    for (int k = 0; k < CH / 256; ++k) {
        int li = k * 256 + tid;
        int i = chunk0 + li;
        if (i < e) {
            int s = src[i], d = dst[i];
            int b = d >> 8;
            int p = lexcl[b] + (int)srank[li];
            sdata[p] = (s << 8) | (d & 255);
            pbuk[p] = (unsigned short)b;
        }
    }
    __syncthreads();

    for (int p = tid; p < cnt; p += 256) {
        int b = pbuk[p];
        adj[sbase[b] + (p - lexcl[b])] = sdata[p];
    }
}

// ---------------- per-bucket node-sort -> adj2 + rowptr + dinv ----------------
__global__ __launch_bounds__(256) void csr_kernel(
        const int* __restrict__ bhist, const int* __restrict__ boffs,
        const int* __restrict__ adj, int* __restrict__ adj2,
        int* __restrict__ rowptr, float* __restrict__ dinv, int n) {
    __shared__ int cnt[256];
    __shared__ int s[256];
    __shared__ int cur[256];
    int tid = threadIdx.x;
    int b = blockIdx.x;
    cnt[tid] = 0;
    __syncthreads();
    int ebeg = boffs[b], ecnt = bhist[b];
    for (int j = tid; j < ecnt; j += 256)
        atomicAdd(&cnt[adj[ebeg + j] & 255], 1);
    __syncthreads();
    int v = cnt[tid];
    s[tid] = v;
    __syncthreads();
    for (int off = 1; off < 256; off <<= 1) {
        int t = (tid >= off) ? s[tid - off] : 0;
        __syncthreads();
        s[tid] += t;
        __syncthreads();
    }
    int excl = s[tid] - v;
    cur[tid] = excl;
    int node = b * 256 + tid;
    if (node < n) {
        rowptr[node] = ebeg + excl;
        dinv[node] = rsqrtf((float)v + 1.0f);
    }
    if (node == n) rowptr[n] = ebeg + excl;   // sentinel: all later cnt are 0
    __syncthreads();
    // scatter confined to this bucket's 32KB window -> L2 write-combines
    for (int j = tid; j < ecnt; j += 256) {
        int w = adj[ebeg + j];
        int p = atomicAdd(&cur[w & 255], 1);
        adj2[ebeg + p] = w >> 8;
    }
}

// ---------------- layer 1 GEMM: g1 = (x @ W1^T) * dinv[row] ----------------
__global__ void gemm1_kernel(const float* __restrict__ x, const float* __restrict__ W1,
                             const float* __restrict__ dinv, float* __restrict__ g1, int n) {
    __shared__ float sWt[64 * 32];
    __shared__ float sX[8 * 64];
    int tid = threadIdx.x;
    for (int idx = tid; idx < 64 * 32; idx += 256) {
        int k = idx >> 5, c = idx & 31;
        sWt[idx] = W1[c * 64 + k];
    }
    int row0 = blockIdx.x * 8;
    for (int idx = tid; idx < 8 * 64; idx += 256) {
        int r = row0 + (idx >> 6);
        sX[idx] = (r < n) ? x[r * 64 + (idx & 63)] : 0.0f;
    }
    __syncthreads();
    int lr = tid >> 5, c = tid & 31;
    int r = row0 + lr;
    if (r < n) {
        float acc = 0.0f;
#pragma unroll
        for (int k = 0; k < 64; ++k) acc += sX[lr * 64 + k] * sWt[k * 32 + c];
        g1[r * 32 + c] = acc * dinv[r];
    }
}

// ---------------- layer 1 aggregation: per-node CSR gather ----------------
__global__ __launch_bounds__(256) void agg1_kernel(
        const int* __restrict__ rowptr, const int* __restrict__ adj2,
        const float* __restrict__ dinv, const float* __restrict__ g1,
        const float* __restrict__ b1, float* __restrict__ agg1, int n) {
    int t = blockIdx.x * blockDim.x + threadIdx.x;
    int node = t >> 5;
    if (node >= n) return;
    int c = t & 31;
    int j = rowptr[node], end = rowptr[node + 1];
    float acc = g1[node * 32 + c];            // self-loop (pre-scaled by dinv)
    for (; j + 3 < end; j += 4) {
        int s0 = adj2[j], s1 = adj2[j + 1], s2 = adj2[j + 2], s3 = adj2[j + 3];
        float v0 = g1[s0 * 32 + c];
        float v1 = g1[s1 * 32 + c];
        float v2 = g1[s2 * 32 + c];
        float v3 = g1[s3 * 32 + c];
        acc += (v0 + v1) + (v2 + v3);
    }
    for (; j < end; ++j) acc += g1[adj2[j] * 32 + c];
    agg1[node * 32 + c] = b1[c] + dinv[node] * acc;
}

// ---------------- layer 2 GEMM: g2 = (relu(agg1) @ W2^T) * dinv[row] ----------------
__global__ void gemm2_kernel(const float* __restrict__ agg1, const float* __restrict__ W2,
                             const float* __restrict__ dinv, float* __restrict__ g2, int n) {
    __shared__ float sWt[32 * 16];
    __shared__ float sH[16 * 32];
    int tid = threadIdx.x;
    for (int idx = tid; idx < 32 * 16; idx += 256) {
        int k = idx >> 4, c = idx & 15;
        sWt[idx] = W2[c * 32 + k];
    }
    int row0 = blockIdx.x * 16;
    for (int idx = tid; idx < 16 * 32; idx += 256) {
        int r = row0 + (idx >> 5);
        float v = (r < n) ? agg1[r * 32 + (idx & 31)] : 0.0f;
        sH[idx] = fmaxf(v, 0.0f);
    }
    __syncthreads();
    int lr = tid >> 4, c = tid & 15;
    int r = row0 + lr;
    if (r < n) {
        float acc = 0.0f;
#pragma unroll
        for (int k = 0; k < 32; ++k) acc += sH[lr * 32 + k] * sWt[k * 16 + c];
        g2[r * 16 + c] = acc * dinv[r];
    }
}

// ---------------- layer 2 aggregation: per-node CSR gather ----------------
__global__ __launch_bounds__(256) void agg2_kernel(
        const int* __restrict__ rowptr, const int* __restrict__ adj2,
        const float* __restrict__ dinv, const float* __restrict__ g2,
        const float* __restrict__ b2, float* __restrict__ z, int n) {
    int t = blockIdx.x * blockDim.x + threadIdx.x;
    int node = t >> 4;
    if (node >= n) return;
    int c = t & 15;
    int j = rowptr[node], end = rowptr[node + 1];
    float acc = g2[node * 16 + c];
    for (; j + 3 < end; j += 4) {
        int s0 = adj2[j], s1 = adj2[j + 1], s2 = adj2[j + 2], s3 = adj2[j + 3];
        float v0 = g2[s0 * 16 + c];
        float v1 = g2[s1 * 16 + c];
        float v2 = g2[s2 * 16 + c];
        float v3 = g2[s3 * 16 + c];
        acc += (v0 + v1) + (v2 + v3);
    }
    for (; j < end; ++j) acc += g2[adj2[j] * 16 + c];
    z[node * 16 + c] = b2[c] + dinv[node] * acc;
}

// ---------------- decode ----------------
__global__ void decode_kernel(const int* __restrict__ src, const int* __restrict__ dst,
                              const float* __restrict__ z, float* __restrict__ out, int e) {
    int i = blockIdx.x * blockDim.x + threadIdx.x;
    if (i < e) {
        int s = src[i], d = dst[i];
        const float4* zs = (const float4*)(z + (size_t)s * 16);
        const float4* zd = (const float4*)(z + (size_t)d * 16);
        float acc = 0.0f;
#pragma unroll
        for (int q = 0; q < 4; ++q) {
            float4 a = zs[q], b = zd[q];
            acc += a.x * b.x + a.y * b.y + a.z * b.z + a.w * b.w;
        }
        out[i] = 1.0f / (1.0f + expf(-acc));
    }
}

extern "C" void kernel_launch(void* const* d_in, const int* in_sizes, int n_in,
                              void* d_out, int out_size, void* d_ws, size_t ws_size,
                              hipStream_t stream) {
    const float* x   = (const float*)d_in[0];
    const int* eidx  = (const int*)d_in[1];
    const float* W1  = (const float*)d_in[2];
    const float* b1  = (const float*)d_in[3];
    const float* W2  = (const float*)d_in[4];
    const float* b2  = (const float*)d_in[5];
    float* out = (float*)d_out;

    const int n = NN;
    const int e = NE;
    const int* src = eidx;
    const int* dst = eidx + e;

    // workspace layout (~52 MB)
    int* bhist   = (int*)d_ws;                 // 512
    int* boffs   = bhist + 512;                // 512
    int* cursor  = boffs + 512;                // 512
    int* rowptr  = cursor + 512;               // NN+1 (pad 100004)
    int* adj     = rowptr + 100004;            // NE (packed src<<8|dstlo; dead after csr)
    int* adj2    = adj + e;                    // NE (node-sorted srcs)
    float* dinv  = (float*)(adj2 + e);         // NN
    float* g1    = (float*)adj;                // alias: NE*4B == NN*32*4B exactly
    float* agg1  = dinv + n;                   // NN*32
    float* g2    = agg1 + (size_t)n * 32;      // NN*16
    float* z     = g2 + (size_t)n * 16;        // NN*16

    dim3 blk(256);

    // CSR build (all writes coalesced or L2-window-confined)
    hipMemsetAsync(bhist, 0, 512 * sizeof(int), stream);
    bhist_kernel<<<1024, blk, 0, stream>>>(dst, bhist, e);
    bscan_kernel<<<1, 512, 0, stream>>>(bhist, boffs, cursor);
    partition_kernel<<<NPART, blk, 0, stream>>>(src, dst, cursor, adj, e);
    csr_kernel<<<NB, blk, 0, stream>>>(bhist, boffs, adj, adj2, rowptr, dinv, n);

    // layer 1
    gemm1_kernel<<<(n + 7) / 8, blk, 0, stream>>>(x, W1, dinv, g1, n);
    agg1_kernel<<<(n * 32) / 256, blk, 0, stream>>>(rowptr, adj2, dinv, g1, b1, agg1, n);

    // layer 2
    gemm2_kernel<<<(n + 15) / 16, blk, 0, stream>>>(agg1, W2, dinv, g2, n);
    agg2_kernel<<<(n * 16) / 256, blk, 0, stream>>>(rowptr, adj2, dinv, g2, b2, z, n);

    // decode
    decode_kernel<<<(e + 255) / 256, blk, 0, stream>>>(src, dst, z, out, e);
}

// Round 5
// 293.965 us; speedup vs baseline: 4.2478x; 1.3353x over previous
//
#include <hip/hip_runtime.h>
#include <hip/hip_fp16.h>
#include <math.h>

#define NN 100000
#define NE 3200000
#define NB 391            // buckets of 256 nodes
#define CH 4096           // edges per partition chunk
#define NPART ((NE + CH - 1) / CH)   // 782

__device__ inline float2 u2f2(unsigned v) {
    __half2 h = *reinterpret_cast<__half2*>(&v);
    return __half22float2(h);
}

// ---------------- bucket histogram: bhist[dst>>8]++ ----------------
__global__ void bhist_kernel(const int* __restrict__ dst, int* __restrict__ bhist, int e) {
    __shared__ int h[NB];
    int tid = threadIdx.x;
    for (int i = tid; i < NB; i += 256) h[i] = 0;
    __syncthreads();
    for (int i = blockIdx.x * blockDim.x + tid; i < e; i += gridDim.x * blockDim.x)
        atomicAdd(&h[dst[i] >> 8], 1);
    __syncthreads();
    for (int i = tid; i < NB; i += 256) if (h[i]) atomicAdd(&bhist[i], h[i]);
}

// ---------------- bucket scan ----------------
__global__ void bscan_kernel(const int* __restrict__ bhist, int* __restrict__ boffs,
                             int* __restrict__ cursor) {
    __shared__ int s[512];
    int tid = threadIdx.x;
    int v = (tid < NB) ? bhist[tid] : 0;
    s[tid] = v;
    __syncthreads();
    for (int off = 1; off < 512; off <<= 1) {
        int t = (tid >= off) ? s[tid - off] : 0;
        __syncthreads();
        s[tid] += t;
        __syncthreads();
    }
    if (tid < NB) {
        int ex = s[tid] - v;
        boffs[tid] = ex;
        cursor[tid] = ex;
    }
}

// ---------------- partition: bucketed counting-sort, LDS-staged coalesced writes ----------------
__global__ __launch_bounds__(256) void partition_kernel(
        const int* __restrict__ src, const int* __restrict__ dst,
        int* __restrict__ cursor, int* __restrict__ adj, int e) {
    __shared__ int scnt[NB];
    __shared__ int sbase[NB];
    __shared__ int lexcl[NB];
    __shared__ int sA[512], sB[512];
    __shared__ int sdata[CH];
    __shared__ unsigned short srank[CH];
    __shared__ unsigned short pbuk[CH];

    int tid = threadIdx.x;
    int chunk0 = blockIdx.x * CH;
    int cnt = e - chunk0; if (cnt > CH) cnt = CH;

    for (int i = tid; i < NB; i += 256) scnt[i] = 0;
    __syncthreads();

    for (int k = 0; k < CH / 256; ++k) {
        int li = k * 256 + tid;
        int i = chunk0 + li;
        if (i < e) {
            int b = dst[i] >> 8;
            int r = atomicAdd(&scnt[b], 1);
            srank[li] = (unsigned short)r;
        }
    }
    __syncthreads();

    for (int b = tid; b < NB; b += 256)
        if (scnt[b]) sbase[b] = atomicAdd(&cursor[b], scnt[b]);

    {
        int* pa = sA; int* pb = sB;
        pa[tid]       = (tid < NB) ? scnt[tid] : 0;
        pa[tid + 256] = (tid + 256 < NB) ? scnt[tid + 256] : 0;
        __syncthreads();
        for (int off = 1; off < 512; off <<= 1) {
            for (int q = tid; q < 512; q += 256)
                pb[q] = pa[q] + ((q >= off) ? pa[q - off] : 0);
            __syncthreads();
            int* t = pa; pa = pb; pb = t;
        }
        if (tid < NB)       lexcl[tid]       = pa[tid]       - scnt[tid];
        if (tid + 256 < NB) lexcl[tid + 256] = pa[tid + 256] - scnt[tid + 256];
    }
    __syncthreads();

    for (int k = 0; k < CH / 256; ++k) {
        int li = k * 256 + tid;
        int i = chunk0 + li;
        if (i < e) {
            int s = src[i], d = dst[i];
            int b = d >> 8;
            int p = lexcl[b] + (int)srank[li];
            sdata[p] = (s << 8) | (d & 255);
            pbuk[p] = (unsigned short)b;
        }
    }
    __syncthreads();

    for (int p = tid; p < cnt; p += 256) {
        int b = pbuk[p];
        adj[sbase[b] + (p - lexcl[b])] = sdata[p];
    }
}

// ---------------- per-bucket node-sort -> adj2 + rowptr + dinv ----------------
__global__ __launch_bounds__(256) void csr_kernel(
        const int* __restrict__ bhist, const int* __restrict__ boffs,
        const int* __restrict__ adj, int* __restrict__ adj2,
        int* __restrict__ rowptr, float* __restrict__ dinv, int n) {
    __shared__ int cnt[256];
    __shared__ int s[256];
    __shared__ int cur[256];
    int tid = threadIdx.x;
    int b = blockIdx.x;
    cnt[tid] = 0;
    __syncthreads();
    int ebeg = boffs[b], ecnt = bhist[b];
    for (int j = tid; j < ecnt; j += 256)
        atomicAdd(&cnt[adj[ebeg + j] & 255], 1);
    __syncthreads();
    int v = cnt[tid];
    s[tid] = v;
    __syncthreads();
    for (int off = 1; off < 256; off <<= 1) {
        int t = (tid >= off) ? s[tid - off] : 0;
        __syncthreads();
        s[tid] += t;
        __syncthreads();
    }
    int excl = s[tid] - v;
    cur[tid] = excl;
    int node = b * 256 + tid;
    if (node < n) {
        rowptr[node] = ebeg + excl;
        dinv[node] = rsqrtf((float)v + 1.0f);
    }
    if (node == n) rowptr[n] = ebeg + excl;   // sentinel == e
    __syncthreads();
    for (int j = tid; j < ecnt; j += 256) {
        int w = adj[ebeg + j];
        int p = atomicAdd(&cur[w & 255], 1);
        adj2[ebeg + p] = w >> 8;
    }
}

// ---------------- layer 1 GEMM: g1h = fp16((x @ W1^T) * dinv[row]) ----------------
__global__ void gemm1_kernel(const float* __restrict__ x, const float* __restrict__ W1,
                             const float* __restrict__ dinv, __half* __restrict__ g1h, int n) {
    __shared__ float sWt[64 * 32];
    __shared__ float sX[8 * 64];
    int tid = threadIdx.x;
    for (int idx = tid; idx < 64 * 32; idx += 256) {
        int k = idx >> 5, c = idx & 31;
        sWt[idx] = W1[c * 64 + k];
    }
    int row0 = blockIdx.x * 8;
    for (int idx = tid; idx < 8 * 64; idx += 256) {
        int r = row0 + (idx >> 6);
        sX[idx] = (r < n) ? x[r * 64 + (idx & 63)] : 0.0f;
    }
    __syncthreads();
    int lr = tid >> 5, c = tid & 31;
    int r = row0 + lr;
    if (r < n) {
        float acc = 0.0f;
#pragma unroll
        for (int k = 0; k < 64; ++k) acc += sX[lr * 64 + k] * sWt[k * 32 + c];
        g1h[r * 32 + c] = __float2half(acc * dinv[r]);
    }
}

// ---------------- layer 1 aggregation: fp16 gathers, 16 lanes/node (2 cols each) ----------------
__global__ __launch_bounds__(256) void agg1_kernel(
        const int* __restrict__ rowptr, const int* __restrict__ adj2,
        const float* __restrict__ dinv, const __half* __restrict__ g1h,
        const float* __restrict__ b1, float* __restrict__ agg1, int n) {
    int t = blockIdx.x * blockDim.x + threadIdx.x;
    int node = t >> 4;
    if (node >= n) return;
    int c2 = t & 15;                           // column pair index
    const unsigned* G = (const unsigned*)g1h;  // [node*16 + c2] = cols {2c2, 2c2+1}
    float2 acc = u2f2(G[node * 16 + c2]);      // self-loop (pre-scaled by dinv)
    int j = rowptr[node], end = rowptr[node + 1];
    for (; j + 3 < end; j += 4) {
        int s0 = adj2[j], s1 = adj2[j + 1], s2 = adj2[j + 2], s3 = adj2[j + 3];
        float2 v0 = u2f2(G[s0 * 16 + c2]);
        float2 v1 = u2f2(G[s1 * 16 + c2]);
        float2 v2 = u2f2(G[s2 * 16 + c2]);
        float2 v3 = u2f2(G[s3 * 16 + c2]);
        acc.x += (v0.x + v1.x) + (v2.x + v3.x);
        acc.y += (v0.y + v1.y) + (v2.y + v3.y);
    }
    for (; j < end; ++j) {
        float2 v = u2f2(G[adj2[j] * 16 + c2]);
        acc.x += v.x; acc.y += v.y;
    }
    float di = dinv[node];
    float2 bb = ((const float2*)b1)[c2];
    float2 outv = make_float2(bb.x + di * acc.x, bb.y + di * acc.y);
    ((float2*)agg1)[node * 16 + c2] = outv;
}

// ---------------- layer 2 GEMM: g2h = fp16((relu(agg1) @ W2^T) * dinv[row]) ----------------
__global__ void gemm2_kernel(const float* __restrict__ agg1, const float* __restrict__ W2,
                             const float* __restrict__ dinv, __half* __restrict__ g2h, int n) {
    __shared__ float sWt[32 * 16];
    __shared__ float sH[16 * 32];
    int tid = threadIdx.x;
    for (int idx = tid; idx < 32 * 16; idx += 256) {
        int k = idx >> 4, c = idx & 15;
        sWt[idx] = W2[c * 32 + k];
    }
    int row0 = blockIdx.x * 16;
    for (int idx = tid; idx < 16 * 32; idx += 256) {
        int r = row0 + (idx >> 5);
        float v = (r < n) ? agg1[r * 32 + (idx & 31)] : 0.0f;
        sH[idx] = fmaxf(v, 0.0f);
    }
    __syncthreads();
    int lr = tid >> 4, c = tid & 15;
    int r = row0 + lr;
    if (r < n) {
        float acc = 0.0f;
#pragma unroll
        for (int k = 0; k < 32; ++k) acc += sH[lr * 32 + k] * sWt[k * 16 + c];
        g2h[r * 16 + c] = __float2half(acc * dinv[r]);
    }
}

// ---------------- layer 2 aggregation: fp16 gathers, 8 lanes/node; z stored fp16 ----------------
__global__ __launch_bounds__(256) void agg2_kernel(
        const int* __restrict__ rowptr, const int* __restrict__ adj2,
        const float* __restrict__ dinv, const __half* __restrict__ g2h,
        const float* __restrict__ b2, __half* __restrict__ zh, int n) {
    int t = blockIdx.x * blockDim.x + threadIdx.x;
    int node = t >> 3;
    if (node >= n) return;
    int c2 = t & 7;
    const unsigned* G = (const unsigned*)g2h;
    float2 acc = u2f2(G[node * 8 + c2]);
    int j = rowptr[node], end = rowptr[node + 1];
    for (; j + 3 < end; j += 4) {
        int s0 = adj2[j], s1 = adj2[j + 1], s2 = adj2[j + 2], s3 = adj2[j + 3];
        float2 v0 = u2f2(G[s0 * 8 + c2]);
        float2 v1 = u2f2(G[s1 * 8 + c2]);
        float2 v2 = u2f2(G[s2 * 8 + c2]);
        float2 v3 = u2f2(G[s3 * 8 + c2]);
        acc.x += (v0.x + v1.x) + (v2.x + v3.x);
        acc.y += (v0.y + v1.y) + (v2.y + v3.y);
    }
    for (; j < end; ++j) {
        float2 v = u2f2(G[adj2[j] * 8 + c2]);
        acc.x += v.x; acc.y += v.y;
    }
    float di = dinv[node];
    float2 bb = ((const float2*)b2)[c2];
    __half2 outv = __float22half2_rn(make_float2(bb.x + di * acc.x, bb.y + di * acc.y));
    ((__half2*)zh)[node * 8 + c2] = outv;
}

// ---------------- decode: fp16 z gathers (table 3.2MB -> L2-resident) ----------------
__device__ inline float dot2u(unsigned a, unsigned b) {
    float2 fa = u2f2(a), fb = u2f2(b);
    return fa.x * fb.x + fa.y * fb.y;
}

__global__ void decode_kernel(const int* __restrict__ src, const int* __restrict__ dst,
                              const __half* __restrict__ zh, float* __restrict__ out, int e) {
    int i = blockIdx.x * blockDim.x + threadIdx.x;
    if (i < e) {
        int s = src[i], d = dst[i];
        const uint4* Zs = (const uint4*)(zh + (size_t)s * 16);
        const uint4* Zd = (const uint4*)(zh + (size_t)d * 16);
        uint4 a0 = Zs[0], a1 = Zs[1];
        uint4 b0 = Zd[0], b1 = Zd[1];
        float acc = dot2u(a0.x, b0.x) + dot2u(a0.y, b0.y)
                  + dot2u(a0.z, b0.z) + dot2u(a0.w, b0.w)
                  + dot2u(a1.x, b1.x) + dot2u(a1.y, b1.y)
                  + dot2u(a1.z, b1.z) + dot2u(a1.w, b1.w);
        out[i] = 1.0f / (1.0f + expf(-acc));
    }
}

extern "C" void kernel_launch(void* const* d_in, const int* in_sizes, int n_in,
                              void* d_out, int out_size, void* d_ws, size_t ws_size,
                              hipStream_t stream) {
    const float* x   = (const float*)d_in[0];
    const int* eidx  = (const int*)d_in[1];
    const float* W1  = (const float*)d_in[2];
    const float* b1  = (const float*)d_in[3];
    const float* W2  = (const float*)d_in[4];
    const float* b2  = (const float*)d_in[5];
    float* out = (float*)d_out;

    const int n = NN;
    const int e = NE;
    const int* src = eidx;
    const int* dst = eidx + e;

    // workspace layout (all segments 16B-aligned)
    int* bhist   = (int*)d_ws;                 // 512
    int* boffs   = bhist + 512;                // 512
    int* cursor  = boffs + 512;                // 512
    int* rowptr  = cursor + 512;               // NN+1 (pad 100004)
    int* adj     = rowptr + 100004;            // NE packed (dead after csr)
    int* adj2    = adj + e;                    // NE node-sorted srcs
    float* dinv  = (float*)(adj2 + e);         // NN
    __half* g1h  = (__half*)adj;               // alias: NN*32 halves (6.4MB) in adj's 12.8MB
    float* agg1  = dinv + n;                   // NN*32 f32
    __half* g2h  = (__half*)(agg1 + (size_t)n * 32);   // NN*16 halves
    __half* zh   = g2h + (size_t)n * 16;               // NN*16 halves

    dim3 blk(256);

    // CSR build
    hipMemsetAsync(bhist, 0, 512 * sizeof(int), stream);
    bhist_kernel<<<1024, blk, 0, stream>>>(dst, bhist, e);
    bscan_kernel<<<1, 512, 0, stream>>>(bhist, boffs, cursor);
    partition_kernel<<<NPART, blk, 0, stream>>>(src, dst, cursor, adj, e);
    csr_kernel<<<NB, blk, 0, stream>>>(bhist, boffs, adj, adj2, rowptr, dinv, n);

    // layer 1
    gemm1_kernel<<<(n + 7) / 8, blk, 0, stream>>>(x, W1, dinv, g1h, n);
    agg1_kernel<<<(n * 16 + 255) / 256, blk, 0, stream>>>(rowptr, adj2, dinv, g1h, b1, agg1, n);

    // layer 2
    gemm2_kernel<<<(n + 15) / 16, blk, 0, stream>>>(agg1, W2, dinv, g2h, n);
    agg2_kernel<<<(n * 8 + 255) / 256, blk, 0, stream>>>(rowptr, adj2, dinv, g2h, b2, zh, n);

    // decode
    decode_kernel<<<(e + 255) / 256, blk, 0, stream>>>(src, dst, zh, out, e);
}

// Round 6
// 272.028 us; speedup vs baseline: 4.5904x; 1.0806x over previous
//
#include <hip/hip_runtime.h>
#include <hip/hip_fp16.h>
#include <math.h>

#define NN 100000
#define NE 3200000
#define NB 391            // buckets of 256 nodes
#define CH 4096           // edges per partition chunk
#define NPART ((NE + CH - 1) / CH)   // 782

__device__ inline float2 u2f2(unsigned v) {
    __half2 h = *reinterpret_cast<__half2*>(&v);
    return __half22float2(h);
}

// ---------------- bucket histogram: bhist[dst>>8]++ ----------------
__global__ void bhist_kernel(const int* __restrict__ dst, int* __restrict__ bhist, int e) {
    __shared__ int h[NB];
    int tid = threadIdx.x;
    for (int i = tid; i < NB; i += 256) h[i] = 0;
    __syncthreads();
    for (int i = blockIdx.x * blockDim.x + tid; i < e; i += gridDim.x * blockDim.x)
        atomicAdd(&h[dst[i] >> 8], 1);
    __syncthreads();
    for (int i = tid; i < NB; i += 256) if (h[i]) atomicAdd(&bhist[i], h[i]);
}

// ---------------- bucket scan ----------------
__global__ void bscan_kernel(const int* __restrict__ bhist, int* __restrict__ boffs,
                             int* __restrict__ cursor) {
    __shared__ int s[512];
    int tid = threadIdx.x;
    int v = (tid < NB) ? bhist[tid] : 0;
    s[tid] = v;
    __syncthreads();
    for (int off = 1; off < 512; off <<= 1) {
        int t = (tid >= off) ? s[tid - off] : 0;
        __syncthreads();
        s[tid] += t;
        __syncthreads();
    }
    if (tid < NB) {
        int ex = s[tid] - v;
        boffs[tid] = ex;
        cursor[tid] = ex;
    }
}

// ---------------- partition: bucketed counting-sort, LDS-staged coalesced writes ----------------
__global__ __launch_bounds__(256) void partition_kernel(
        const int* __restrict__ src, const int* __restrict__ dst,
        int* __restrict__ cursor, int* __restrict__ adj, int e) {
    __shared__ int scnt[NB];
    __shared__ int sbase[NB];
    __shared__ int lexcl[NB];
    __shared__ int sA[512], sB[512];
    __shared__ int sdata[CH];
    __shared__ unsigned short srank[CH];
    __shared__ unsigned short pbuk[CH];

    int tid = threadIdx.x;
    int chunk0 = blockIdx.x * CH;
    int cnt = e - chunk0; if (cnt > CH) cnt = CH;

    for (int i = tid; i < NB; i += 256) scnt[i] = 0;
    __syncthreads();

    for (int k = 0; k < CH / 256; ++k) {
        int li = k * 256 + tid;
        int i = chunk0 + li;
        if (i < e) {
            int b = dst[i] >> 8;
            int r = atomicAdd(&scnt[b], 1);
            srank[li] = (unsigned short)r;
        }
    }
    __syncthreads();

    for (int b = tid; b < NB; b += 256)
        if (scnt[b]) sbase[b] = atomicAdd(&cursor[b], scnt[b]);

    {
        int* pa = sA; int* pb = sB;
        pa[tid]       = (tid < NB) ? scnt[tid] : 0;
        pa[tid + 256] = (tid + 256 < NB) ? scnt[tid + 256] : 0;
        __syncthreads();
        for (int off = 1; off < 512; off <<= 1) {
            for (int q = tid; q < 512; q += 256)
                pb[q] = pa[q] + ((q >= off) ? pa[q - off] : 0);
            __syncthreads();
            int* t = pa; pa = pb; pb = t;
        }
        if (tid < NB)       lexcl[tid]       = pa[tid]       - scnt[tid];
        if (tid + 256 < NB) lexcl[tid + 256] = pa[tid + 256] - scnt[tid + 256];
    }
    __syncthreads();

    for (int k = 0; k < CH / 256; ++k) {
        int li = k * 256 + tid;
        int i = chunk0 + li;
        if (i < e) {
            int s = src[i], d = dst[i];
            int b = d >> 8;
            int p = lexcl[b] + (int)srank[li];
            sdata[p] = (s << 8) | (d & 255);
            pbuk[p] = (unsigned short)b;
        }
    }
    __syncthreads();

    for (int p = tid; p < cnt; p += 256) {
        int b = pbuk[p];
        adj[sbase[b] + (p - lexcl[b])] = sdata[p];
    }
}

// ---------------- per-bucket node-sort -> adj2 + rowptr + dinv ----------------
__global__ __launch_bounds__(256) void csr_kernel(
        const int* __restrict__ bhist, const int* __restrict__ boffs,
        const int* __restrict__ adj, int* __restrict__ adj2,
        int* __restrict__ rowptr, float* __restrict__ dinv, int n) {
    __shared__ int cnt[256];
    __shared__ int s[256];
    __shared__ int cur[256];
    int tid = threadIdx.x;
    int b = blockIdx.x;
    cnt[tid] = 0;
    __syncthreads();
    int ebeg = boffs[b], ecnt = bhist[b];
    for (int j = tid; j < ecnt; j += 256)
        atomicAdd(&cnt[adj[ebeg + j] & 255], 1);
    __syncthreads();
    int v = cnt[tid];
    s[tid] = v;
    __syncthreads();
    for (int off = 1; off < 256; off <<= 1) {
        int t = (tid >= off) ? s[tid - off] : 0;
        __syncthreads();
        s[tid] += t;
        __syncthreads();
    }
    int excl = s[tid] - v;
    cur[tid] = excl;
    int node = b * 256 + tid;
    if (node < n) {
        rowptr[node] = ebeg + excl;
        dinv[node] = rsqrtf((float)v + 1.0f);
    }
    if (node == n) rowptr[n] = ebeg + excl;   // sentinel == e
    __syncthreads();
    for (int j = tid; j < ecnt; j += 256) {
        int w = adj[ebeg + j];
        int p = atomicAdd(&cur[w & 255], 1);
        adj2[ebeg + p] = w >> 8;
    }
}

// ---------------- layer 1 GEMM: split fp16 tables g1a (cols 0-15), g1b (cols 16-31) ----------------
// block = 256 threads, tile 32 rows; thread = (row r=tid>>3, colgroup cg=tid&7 -> cols 4cg..4cg+3)
__global__ __launch_bounds__(256) void gemm1_kernel(
        const float* __restrict__ x, const float* __restrict__ W1,
        const float* __restrict__ dinv, __half* __restrict__ g1a,
        __half* __restrict__ g1b, int n) {
    __shared__ float sW[64 * 32];     // sW[k*32+c] = W1[c*64+k]
    __shared__ float sX[32 * 65];     // padded stride 65 -> bank (r+k)&31
    int tid = threadIdx.x;
    for (int idx = tid; idx < 2048; idx += 256) {
        int k = idx >> 5, c = idx & 31;
        sW[idx] = W1[c * 64 + k];
    }
    int row0 = blockIdx.x * 32;
    for (int idx = tid; idx < 512; idx += 256) {   // 512 float4 = 32 rows x 16
        int r = idx >> 4, q = idx & 15;
        int grow = row0 + r;
        float4 v = (grow < n) ? ((const float4*)x)[(size_t)grow * 16 + q]
                              : make_float4(0.f, 0.f, 0.f, 0.f);
        float* dp = &sX[r * 65 + q * 4];
        dp[0] = v.x; dp[1] = v.y; dp[2] = v.z; dp[3] = v.w;
    }
    __syncthreads();
    int r = tid >> 3, cg = tid & 7;
    const float4* sW4 = (const float4*)sW;
    float4 acc = make_float4(0.f, 0.f, 0.f, 0.f);
#pragma unroll
    for (int k = 0; k < 64; ++k) {
        float xk = sX[r * 65 + k];
        float4 w = sW4[k * 8 + cg];
        acc.x += xk * w.x; acc.y += xk * w.y; acc.z += xk * w.z; acc.w += xk * w.w;
    }
    int grow = row0 + r;
    if (grow < n) {
        float di = dinv[grow];
        __half2 h0 = __float22half2_rn(make_float2(acc.x * di, acc.y * di));
        __half2 h1 = __float22half2_rn(make_float2(acc.z * di, acc.w * di));
        uint2 packed;
        packed.x = *(unsigned*)&h0;
        packed.y = *(unsigned*)&h1;
        if (cg < 4) ((uint2*)g1a)[(size_t)grow * 4 + cg] = packed;
        else        ((uint2*)g1b)[(size_t)grow * 4 + (cg - 4)] = packed;
    }
}

// ---------------- layer 1 aggregation: one 3.2MB half-table per pass (L2-resident) ----------------
// 8 lanes/node, each lane = 2 cols of the 16-col half
__global__ __launch_bounds__(256) void agg1_kernel(
        const int* __restrict__ rowptr, const int* __restrict__ adj2,
        const float* __restrict__ dinv, const __half* __restrict__ gh,
        const float* __restrict__ b1, float* __restrict__ agg1, int n, int pass) {
    int t = blockIdx.x * blockDim.x + threadIdx.x;
    int node = t >> 3;
    if (node >= n) return;
    int c2 = t & 7;
    const unsigned* G = (const unsigned*)gh;   // [node*8 + c2]
    float2 acc = u2f2(G[(size_t)node * 8 + c2]);   // self-loop (pre-scaled by dinv)
    int j = rowptr[node], end = rowptr[node + 1];
    for (; j + 3 < end; j += 4) {
        int s0 = adj2[j], s1 = adj2[j + 1], s2 = adj2[j + 2], s3 = adj2[j + 3];
        float2 v0 = u2f2(G[(size_t)s0 * 8 + c2]);
        float2 v1 = u2f2(G[(size_t)s1 * 8 + c2]);
        float2 v2 = u2f2(G[(size_t)s2 * 8 + c2]);
        float2 v3 = u2f2(G[(size_t)s3 * 8 + c2]);
        acc.x += (v0.x + v1.x) + (v2.x + v3.x);
        acc.y += (v0.y + v1.y) + (v2.y + v3.y);
    }
    for (; j < end; ++j) {
        float2 v = u2f2(G[(size_t)adj2[j] * 8 + c2]);
        acc.x += v.x; acc.y += v.y;
    }
    float di = dinv[node];
    float2 bb = ((const float2*)b1)[pass * 8 + c2];
    float2 outv = make_float2(bb.x + di * acc.x, bb.y + di * acc.y);
    ((float2*)agg1)[(size_t)node * 16 + pass * 8 + c2] = outv;
}

// ---------------- layer 2 GEMM: 64-row tile, float4 W reads ----------------
// thread = (row r=tid>>2, colgroup cg=tid&3 -> cols 4cg..4cg+3 of 16)
__global__ __launch_bounds__(256) void gemm2_kernel(
        const float* __restrict__ agg1, const float* __restrict__ W2,
        const float* __restrict__ dinv, __half* __restrict__ g2h, int n) {
    __shared__ float sW[32 * 16];     // sW[k*16+c] = W2[c*32+k]
    __shared__ float sH[64 * 33];     // padded
    int tid = threadIdx.x;
    for (int idx = tid; idx < 512; idx += 256) {
        int k = idx >> 4, c = idx & 15;
        sW[idx] = W2[c * 32 + k];
    }
    int row0 = blockIdx.x * 64;
    for (int idx = tid; idx < 512; idx += 256) {   // 512 float4 = 64 rows x 8
        int r = idx >> 3, q = idx & 7;
        int grow = row0 + r;
        float4 v = (grow < n) ? ((const float4*)agg1)[(size_t)grow * 8 + q]
                              : make_float4(0.f, 0.f, 0.f, 0.f);
        float* dp = &sH[r * 33 + q * 4];
        dp[0] = fmaxf(v.x, 0.f); dp[1] = fmaxf(v.y, 0.f);
        dp[2] = fmaxf(v.z, 0.f); dp[3] = fmaxf(v.w, 0.f);
    }
    __syncthreads();
    int r = tid >> 2, cg = tid & 3;
    const float4* sW4 = (const float4*)sW;
    float4 acc = make_float4(0.f, 0.f, 0.f, 0.f);
#pragma unroll
    for (int k = 0; k < 32; ++k) {
        float hk = sH[r * 33 + k];
        float4 w = sW4[k * 4 + cg];
        acc.x += hk * w.x; acc.y += hk * w.y; acc.z += hk * w.z; acc.w += hk * w.w;
    }
    int grow = row0 + r;
    if (grow < n) {
        float di = dinv[grow];
        __half2 h0 = __float22half2_rn(make_float2(acc.x * di, acc.y * di));
        __half2 h1 = __float22half2_rn(make_float2(acc.z * di, acc.w * di));
        uint2 packed;
        packed.x = *(unsigned*)&h0;
        packed.y = *(unsigned*)&h1;
        ((uint2*)g2h)[(size_t)grow * 4 + cg] = packed;
    }
}

// ---------------- layer 2 aggregation: 3.2MB table already L2-fit ----------------
__global__ __launch_bounds__(256) void agg2_kernel(
        const int* __restrict__ rowptr, const int* __restrict__ adj2,
        const float* __restrict__ dinv, const __half* __restrict__ g2h,
        const float* __restrict__ b2, __half* __restrict__ zh, int n) {
    int t = blockIdx.x * blockDim.x + threadIdx.x;
    int node = t >> 3;
    if (node >= n) return;
    int c2 = t & 7;
    const unsigned* G = (const unsigned*)g2h;
    float2 acc = u2f2(G[(size_t)node * 8 + c2]);
    int j = rowptr[node], end = rowptr[node + 1];
    for (; j + 3 < end; j += 4) {
        int s0 = adj2[j], s1 = adj2[j + 1], s2 = adj2[j + 2], s3 = adj2[j + 3];
        float2 v0 = u2f2(G[(size_t)s0 * 8 + c2]);
        float2 v1 = u2f2(G[(size_t)s1 * 8 + c2]);
        float2 v2 = u2f2(G[(size_t)s2 * 8 + c2]);
        float2 v3 = u2f2(G[(size_t)s3 * 8 + c2]);
        acc.x += (v0.x + v1.x) + (v2.x + v3.x);
        acc.y += (v0.y + v1.y) + (v2.y + v3.y);
    }
    for (; j < end; ++j) {
        float2 v = u2f2(G[(size_t)adj2[j] * 8 + c2]);
        acc.x += v.x; acc.y += v.y;
    }
    float di = dinv[node];
    float2 bb = ((const float2*)b2)[c2];
    __half2 outv = __float22half2_rn(make_float2(bb.x + di * acc.x, bb.y + di * acc.y));
    ((__half2*)zh)[(size_t)node * 8 + c2] = outv;
}

// ---------------- decode: fp16 z gathers (3.2MB table, L2-resident) ----------------
__device__ inline float dot2u(unsigned a, unsigned b) {
    float2 fa = u2f2(a), fb = u2f2(b);
    return fa.x * fb.x + fa.y * fb.y;
}

__global__ void decode_kernel(const int* __restrict__ src, const int* __restrict__ dst,
                              const __half* __restrict__ zh, float* __restrict__ out, int e) {
    int i = blockIdx.x * blockDim.x + threadIdx.x;
    if (i < e) {
        int s = src[i], d = dst[i];
        const uint4* Zs = (const uint4*)(zh + (size_t)s * 16);
        const uint4* Zd = (const uint4*)(zh + (size_t)d * 16);
        uint4 a0 = Zs[0], a1 = Zs[1];
        uint4 b0 = Zd[0], b1 = Zd[1];
        float acc = dot2u(a0.x, b0.x) + dot2u(a0.y, b0.y)
                  + dot2u(a0.z, b0.z) + dot2u(a0.w, b0.w)
                  + dot2u(a1.x, b1.x) + dot2u(a1.y, b1.y)
                  + dot2u(a1.z, b1.z) + dot2u(a1.w, b1.w);
        out[i] = 1.0f / (1.0f + expf(-acc));
    }
}

extern "C" void kernel_launch(void* const* d_in, const int* in_sizes, int n_in,
                              void* d_out, int out_size, void* d_ws, size_t ws_size,
                              hipStream_t stream) {
    const float* x   = (const float*)d_in[0];
    const int* eidx  = (const int*)d_in[1];
    const float* W1  = (const float*)d_in[2];
    const float* b1  = (const float*)d_in[3];
    const float* W2  = (const float*)d_in[4];
    const float* b2  = (const float*)d_in[5];
    float* out = (float*)d_out;

    const int n = NN;
    const int e = NE;
    const int* src = eidx;
    const int* dst = eidx + e;

    // workspace layout (all segments 16B-aligned)
    int* bhist   = (int*)d_ws;                 // 512
    int* boffs   = bhist + 512;                // 512
    int* cursor  = boffs + 512;                // 512
    int* rowptr  = cursor + 512;               // NN+1 (pad 100004)
    int* adj     = rowptr + 100004;            // NE packed (dead after csr)
    int* adj2    = adj + e;                    // NE node-sorted srcs
    float* dinv  = (float*)(adj2 + e);         // NN
    __half* g1a  = (__half*)adj;               // alias: NN*16 halves (3.2MB) - cols 0..15
    __half* g1b  = g1a + (size_t)n * 16;       // NN*16 halves (3.2MB) - cols 16..31
    float* agg1  = dinv + n;                   // NN*32 f32
    __half* g2h  = (__half*)(agg1 + (size_t)n * 32);   // NN*16 halves
    __half* zh   = g2h + (size_t)n * 16;               // NN*16 halves

    dim3 blk(256);

    // CSR build
    hipMemsetAsync(bhist, 0, 512 * sizeof(int), stream);
    bhist_kernel<<<1024, blk, 0, stream>>>(dst, bhist, e);
    bscan_kernel<<<1, 512, 0, stream>>>(bhist, boffs, cursor);
    partition_kernel<<<NPART, blk, 0, stream>>>(src, dst, cursor, adj, e);
    csr_kernel<<<NB, blk, 0, stream>>>(bhist, boffs, adj, adj2, rowptr, dinv, n);

    // layer 1
    gemm1_kernel<<<(n + 31) / 32, blk, 0, stream>>>(x, W1, dinv, g1a, g1b, n);
    agg1_kernel<<<(n * 8 + 255) / 256, blk, 0, stream>>>(rowptr, adj2, dinv, g1a, b1, agg1, n, 0);
    agg1_kernel<<<(n * 8 + 255) / 256, blk, 0, stream>>>(rowptr, adj2, dinv, g1b, b1, agg1, n, 1);

    // layer 2
    gemm2_kernel<<<(n + 63) / 64, blk, 0, stream>>>(agg1, W2, dinv, g2h, n);
    agg2_kernel<<<(n * 8 + 255) / 256, blk, 0, stream>>>(rowptr, adj2, dinv, g2h, b2, zh, n);

    // decode
    decode_kernel<<<(e + 255) / 256, blk, 0, stream>>>(src, dst, zh, out, e);
}